// Round 1
// baseline (309.068 us; speedup 1.0000x reference)
//
#include <hip/hip_runtime.h>
#include <hip/hip_bf16.h>
#include <stdint.h>

// Problem constants (fixed by the reference setup_inputs)
#define BATCH  16384
#define D_IN   1024
#define M_HID  4096
#define R_LORA 16
#define SCALING 2.0f   // ALPHA/R = 32/16

// R6 theory: k_strip (R5) is W_eff-stream-bound: 256 blocks x 8.4 MB = 2.15 GB
// through L2/LLC in 147us = 14.6 TB/s (wb doesn't fit per-XCD L2 -> LLC stream).
// Fix: 128-row x 2048-col blocks (halve the stream to 1.07 GB, double MFMA per
// wf byte) + XCD-pinned M-half (per-XCD working set 4.19MB ~ L2-resident) +
// K-chunked double-buffered x staging (x strip no longer fits LDS) + per-pass
// W2-fold into LDS accumulator (keeps VGPR under the 2-waves/SIMD cap).
// Also: k_wprep reads were fully uncoalesced (4KB lane stride) - transposed id
// mapping makes W0/A reads coalesced, writes scattered (same wb layout).

#define STRIP    64          // legacy fallback path
#define NTHREADS 512

typedef __bf16 bf16x8 __attribute__((ext_vector_type(8)));
typedef float  f32x16 __attribute__((ext_vector_type(16)));

__device__ __forceinline__ unsigned f2bf(float f) {
    union { float f; unsigned u; } c; c.f = f;
    unsigned u = c.u;
    return ((u + 0x7FFFu + ((u >> 16) & 1u)) >> 16);
}

// ---------------- prep: W_eff -> fragment-ordered bf16 ----------------
// Layout (shorts): n32*32768 + c*256 + rl*8 holds W_eff[n32*32+rl][c*8 .. c*8+8).
// R6: id -> (c low bits): W0 read = 64 lanes x 32B contiguous (coalesced),
// A reads coalesced, B-row wave-uniform. Writes scatter (cheap, no stall).
__global__ __launch_bounds__(256) void k_wprep(
    const float* __restrict__ W0, const float* __restrict__ A,
    const float* __restrict__ Bl, unsigned short* __restrict__ wb)
{
    int id  = blockIdx.x * 256 + threadIdx.x;      // 524288 total
    int c   = id & 127;
    int rl  = (id >> 7) & 31;
    int n32 = id >> 12;
    int n = n32 * 32 + rl, k0 = c * 8;
    const float* wr = W0 + (size_t)n * D_IN + k0;
    float4 v0 = *(const float4*)(wr);
    float4 v1 = *(const float4*)(wr + 4);
    const float* brow = Bl + n * R_LORA;
#pragma unroll
    for (int r = 0; r < R_LORA; ++r) {
        float s = SCALING * brow[r];
        const float* ar = A + r * D_IN + k0;
        float4 a0 = *(const float4*)(ar);
        float4 a1 = *(const float4*)(ar + 4);
        v0.x += s * a0.x; v0.y += s * a0.y; v0.z += s * a0.z; v0.w += s * a0.w;
        v1.x += s * a1.x; v1.y += s * a1.y; v1.z += s * a1.z; v1.w += s * a1.w;
    }
    uint4 o;
    o.x = f2bf(v0.x) | (f2bf(v0.y) << 16);
    o.y = f2bf(v0.z) | (f2bf(v0.w) << 16);
    o.z = f2bf(v1.x) | (f2bf(v1.y) << 16);
    o.w = f2bf(v1.z) | (f2bf(v1.w) << 16);
    *(uint4*)(&wb[(size_t)n32 * 32768 + c * 256 + rl * 8]) = o;
}

// ---------------- R6 main kernel: 128 rows x 2048 cols per block ----------------
// 256 blocks (1/CU). XCD-pinned: mhalf = bit2 of blockIdx (bid%8 ~ XCD).
// LDS: double-buffered x chunk As[2][128 rows][32 oct][8], XOR-swizzled
// (cc ^= row&31) so staging ds_write AND fragment ds_read are conflict-free.
// Per pass (64 cols/wave): K-loop over 4 chunks; W2-fold+shuffle-reduce per
// pass into redacc[8][128] (frees rowpart regs; acc[4][2]=128 VGPR dominates).
__global__ __launch_bounds__(512, 2) void k_strip128(
    const float* __restrict__ xf, const unsigned short* __restrict__ wb,
    const float* __restrict__ b0, const float* __restrict__ W2,
    float* __restrict__ part)
{
    __shared__ unsigned short As[2 * 32768];   // 128 KiB
    __shared__ float redacc[8][128];           // 4 KiB

    const int tid  = threadIdx.x;
    const int lane = tid & 63;
    const int wave = tid >> 6;
    const int rl   = lane & 31;
    const int half = lane >> 5;

    const int b     = blockIdx.x;
    const int mhalf = (b >> 2) & 1;                    // XCDs 0-3 -> half 0, 4-7 -> half 1
    const int strip = (b & 3) * 32 + (b >> 3);         // bijective
    const int row0  = strip * 128;

    // zero the cross-wave accumulator
    ((float*)redacc)[tid]       = 0.f;
    ((float*)redacc)[tid + 512] = 0.f;

    // staging decomposition: thread -> (octet, base row)
    const int so  = tid & 31;      // K-octet within chunk
    const int sr0 = tid >> 5;      // 0..15; rows sr0 + j*16

    // ---- prologue: stage chunk 0 -> buf 0 ----
    {
        const float* xsrc = xf + (size_t)row0 * D_IN + so * 8;
        uint4 st[8];
#pragma unroll
        for (int j = 0; j < 8; ++j) {
            const float* p = xsrc + (size_t)(sr0 + j * 16) * D_IN;
            float4 v0 = *(const float4*)(p);
            float4 v1 = *(const float4*)(p + 4);
            st[j].x = f2bf(v0.x) | (f2bf(v0.y) << 16);
            st[j].y = f2bf(v0.z) | (f2bf(v0.w) << 16);
            st[j].z = f2bf(v1.x) | (f2bf(v1.y) << 16);
            st[j].w = f2bf(v1.z) | (f2bf(v1.w) << 16);
        }
#pragma unroll
        for (int j = 0; j < 8; ++j) {
            int row = sr0 + j * 16;
            int cs  = so ^ (row & 31);
            *(uint4*)(&As[row * 256 + cs * 8]) = st[j];
        }
    }
    __syncthreads();

    f32x16 acc[4][2];
    bf16x8 wf0[2], wf1[2];
    const unsigned short* w0p = wb;
    const unsigned short* w1p = wb;
    float b0a = 0.f, b0b = 0.f, w2a = 0.f, w2b = 0.f;

    for (int e = 0; e < 16; ++e) {             // 4 passes x 4 K-chunks
        const int pass = e >> 2, kc = e & 3, cb = e & 1;

        if (kc == 0) {                         // pass setup
            const int n0  = mhalf * 2048 + pass * 512 + wave * 64;
            const int n32 = n0 >> 5;
            w0p = wb + (size_t)n32 * 32768 + half * 256 + rl * 8;
            w1p = w0p + 32768;
            b0a = b0[n0 + rl];      b0b = b0[n0 + 32 + rl];
            w2a = W2[n0 + rl];      w2b = W2[n0 + 32 + rl];
#pragma unroll
            for (int ti = 0; ti < 4; ++ti)
#pragma unroll
                for (int cj = 0; cj < 2; ++cj)
#pragma unroll
                    for (int r = 0; r < 16; ++r) acc[ti][cj][r] = 0.f;
#pragma unroll
            for (int p2 = 0; p2 < 2; ++p2) {   // wf pipeline fill (distance 2)
                wf0[p2] = *(const bf16x8*)(w0p + p2 * 512);
                wf1[p2] = *(const bf16x8*)(w1p + p2 * 512);
            }
        }

        // T14-style staging: issue loads + convert now, ds_write after compute
        uint4 st[8];
        const bool do_stage = (e < 15);
        if (do_stage) {
            const int nkc = (e + 1) & 3;
            const float* xsrc = xf + (size_t)row0 * D_IN + nkc * 256 + so * 8;
#pragma unroll
            for (int j = 0; j < 8; ++j) {
                const float* p = xsrc + (size_t)(sr0 + j * 16) * D_IN;
                float4 v0 = *(const float4*)(p);
                float4 v1 = *(const float4*)(p + 4);
                st[j].x = f2bf(v0.x) | (f2bf(v0.y) << 16);
                st[j].y = f2bf(v0.z) | (f2bf(v0.w) << 16);
                st[j].z = f2bf(v1.x) | (f2bf(v1.y) << 16);
                st[j].w = f2bf(v1.z) | (f2bf(v1.w) << 16);
            }
        }

        // compute 16 K-iters from buf cb
        const unsigned short* Ab = As + cb * 32768;
#pragma unroll 4
        for (int kk = 0; kk < 16; ++kk) {
            const int kkg = kc * 16 + kk;      // 0..63 within pass
            const int cur = kkg & 1;
            const int oc  = kk * 2 + half;     // K-octet within chunk
            bf16x8 af[4];
#pragma unroll
            for (int ti = 0; ti < 4; ++ti) {
                const int row = ti * 32 + rl;
                af[ti] = *(const bf16x8*)(Ab + row * 256 + ((oc ^ rl) << 3));
            }
            bf16x8 w0c = wf0[cur], w1c = wf1[cur];
            if (kkg < 62) {                    // distance-2 register prefetch
                wf0[cur] = *(const bf16x8*)(w0p + (kkg + 2) * 512);
                wf1[cur] = *(const bf16x8*)(w1p + (kkg + 2) * 512);
            }
#pragma unroll
            for (int ti = 0; ti < 4; ++ti) {
                acc[ti][0] = __builtin_amdgcn_mfma_f32_32x32x16_bf16(af[ti], w0c, acc[ti][0], 0, 0, 0);
                acc[ti][1] = __builtin_amdgcn_mfma_f32_32x32x16_bf16(af[ti], w1c, acc[ti][1], 0, 0, 0);
            }
        }

        if (kc == 3) {
            // fold this pass: relu(h+b0) dot W2, reduce over 32 col-lanes,
            // accumulate into per-wave LDS slots (rows are block-global).
            // C/D layout: col = lane&31, row = (r&3) + 8*(r>>2) + 4*half
#pragma unroll
            for (int ti = 0; ti < 4; ++ti)
#pragma unroll
                for (int r = 0; r < 16; ++r) {
                    float p = fmaxf(acc[ti][0][r] + b0a, 0.f) * w2a
                            + fmaxf(acc[ti][1][r] + b0b, 0.f) * w2b;
#pragma unroll
                    for (int m = 1; m <= 16; m <<= 1)
                        p += __shfl_xor(p, m, 64);       // stays within 32-half
                    if (rl == 0)
                        redacc[wave][ti * 32 + (r & 3) + 8 * (r >> 2) + 4 * half] += p;
                }
        }

        if (do_stage) {
#pragma unroll
            for (int j = 0; j < 8; ++j) {
                int row = sr0 + j * 16;
                int cs  = so ^ (row & 31);
                *(uint4*)(&As[(cb ^ 1) * 32768 + row * 256 + cs * 8]) = st[j];
            }
        }
        __syncthreads();
    }

    if (tid < 128) {
        float s = 0.f;
#pragma unroll
        for (int w = 0; w < 8; ++w) s += redacc[w][tid];
        part[(size_t)mhalf * BATCH + row0 + tid] = s;
    }
}

__global__ __launch_bounds__(256) void k_reduce(
    const float* __restrict__ part, const float* __restrict__ b2,
    float* __restrict__ out)
{
    int i = blockIdx.x * 256 + threadIdx.x;
    out[i] = part[i] + part[BATCH + i] + b2[0];
}

// ---------------- legacy fallback (R5 kernel, ws == wb only) ----------------
__global__ __launch_bounds__(NTHREADS, 2) void k_strip(
    const float* __restrict__ xf, const unsigned short* __restrict__ wb,
    const float* __restrict__ b0, const float* __restrict__ W2,
    const float* __restrict__ b2, float* __restrict__ out)
{
    __shared__ unsigned short As[STRIP * D_IN];   // 128 KiB
    __shared__ float red[8][STRIP];               // 2 KiB

    const int tid  = threadIdx.x;
    const int lane = tid & 63;
    const int wave = tid >> 6;
    const int rl   = lane & 31;
    const int half = lane >> 5;
    const int row0 = blockIdx.x * STRIP;

    {
        const int r  = tid >> 3;
        const int c0 = tid & 7;
        const float* xr = xf + (size_t)(row0 + r) * D_IN;
#pragma unroll
        for (int i = 0; i < 16; ++i) {
            int c = i * 8 + c0;
            float4 v0 = *(const float4*)(xr + c * 8);
            float4 v1 = *(const float4*)(xr + c * 8 + 4);
            uint4 o;
            o.x = f2bf(v0.x) | (f2bf(v0.y) << 16);
            o.y = f2bf(v0.z) | (f2bf(v0.w) << 16);
            o.z = f2bf(v1.x) | (f2bf(v1.y) << 16);
            o.w = f2bf(v1.z) | (f2bf(v1.w) << 16);
            *(uint4*)(&As[c * 512 + r * 8]) = o;
        }
    }
    __syncthreads();

    float rowpart[2][16];
#pragma unroll
    for (int ti = 0; ti < 2; ++ti)
#pragma unroll
        for (int r = 0; r < 16; ++r) rowpart[ti][r] = 0.f;

    for (int pass = 0; pass < 8; ++pass) {
        const int n0 = wave * 64 + pass * 512;
        const float w2a = W2[n0 + rl],      b0a = b0[n0 + rl];
        const float w2b = W2[n0 + 32 + rl], b0b = b0[n0 + 32 + rl];
        const int n32 = wave * 2 + pass * 16;
        const unsigned short* w0p = wb + (size_t)n32 * 32768 + half * 256 + rl * 8;
        const unsigned short* w1p = w0p + 32768;

        f32x16 acc[2][2] = {};
        bf16x8 wf0[4], wf1[4];
#pragma unroll
        for (int p = 0; p < 4; ++p) {
            wf0[p] = *(const bf16x8*)(w0p + p * 512);
            wf1[p] = *(const bf16x8*)(w1p + p * 512);
        }

#pragma unroll 4
        for (int kk = 0; kk < 64; ++kk) {
            const int cur = kk & 3;
            const int coff = (kk * 2 + half) * 512 + rl * 8;
            bf16x8 af0 = *(const bf16x8*)(&As[coff]);
            bf16x8 af1 = *(const bf16x8*)(&As[coff + 256]);
            bf16x8 w0c = wf0[cur], w1c = wf1[cur];
            if (kk < 60) {
                wf0[cur] = *(const bf16x8*)(w0p + (kk + 4) * 512);
                wf1[cur] = *(const bf16x8*)(w1p + (kk + 4) * 512);
            }
            acc[0][0] = __builtin_amdgcn_mfma_f32_32x32x16_bf16(af0, w0c, acc[0][0], 0, 0, 0);
            acc[0][1] = __builtin_amdgcn_mfma_f32_32x32x16_bf16(af0, w1c, acc[0][1], 0, 0, 0);
            acc[1][0] = __builtin_amdgcn_mfma_f32_32x32x16_bf16(af1, w0c, acc[1][0], 0, 0, 0);
            acc[1][1] = __builtin_amdgcn_mfma_f32_32x32x16_bf16(af1, w1c, acc[1][1], 0, 0, 0);
        }

#pragma unroll
        for (int ti = 0; ti < 2; ++ti)
#pragma unroll
            for (int r = 0; r < 16; ++r)
                rowpart[ti][r] += fmaxf(acc[ti][0][r] + b0a, 0.f) * w2a
                                + fmaxf(acc[ti][1][r] + b0b, 0.f) * w2b;
    }

#pragma unroll
    for (int ti = 0; ti < 2; ++ti)
#pragma unroll
        for (int r = 0; r < 16; ++r) {
            float p = rowpart[ti][r];
#pragma unroll
            for (int m = 1; m <= 16; m <<= 1)
                p += __shfl_xor(p, m, 64);
            if (rl == 0)
                red[wave][ti * 32 + (r & 3) + 8 * (r >> 2) + 4 * half] = p;
        }
    __syncthreads();
    if (tid < STRIP) {
        float s = b2[0];
#pragma unroll
        for (int w = 0; w < 8; ++w) s += red[w][tid];
        out[row0 + tid] = s;
    }
}

// ---------------- naive fallback (correctness only) ----------------
__global__ __launch_bounds__(256) void k_naive(
    const float* __restrict__ x, const float* __restrict__ W0,
    const float* __restrict__ b0, const float* __restrict__ A,
    const float* __restrict__ Bl, const float* __restrict__ W2,
    const float* __restrict__ b2, float* __restrict__ out)
{
    __shared__ float xs[D_IN];
    int b = blockIdx.x;
    for (int d = threadIdx.x; d < D_IN; d += 256) xs[d] = x[(size_t)b * D_IN + d];
    __syncthreads();
    float part = 0.f;
    for (int m = threadIdx.x; m < M_HID; m += 256) {
        float h = b0[m];
        const float* wr = W0 + (size_t)m * D_IN;
        const float* brow = Bl + m * R_LORA;
        for (int d = 0; d < D_IN; ++d) {
            float w = wr[d];
            for (int r = 0; r < R_LORA; ++r) w += SCALING * brow[r] * A[r * D_IN + d];
            h += xs[d] * w;
        }
        part += fmaxf(h, 0.f) * W2[m];
    }
    __shared__ float sred[256];
    sred[threadIdx.x] = part;
    __syncthreads();
    for (int s = 128; s > 0; s >>= 1) {
        if (threadIdx.x < s) sred[threadIdx.x] += sred[threadIdx.x + s];
        __syncthreads();
    }
    if (threadIdx.x == 0) out[b] = sred[0] + b2[0];
}

// ---------------- host ----------------
extern "C" void kernel_launch(void* const* d_in, const int* in_sizes, int n_in,
                              void* d_out, int out_size, void* d_ws, size_t ws_size,
                              hipStream_t stream) {
    const float* x  = (const float*)d_in[0];
    const float* W0 = (const float*)d_in[1];
    const float* b0 = (const float*)d_in[2];
    const float* A  = (const float*)d_in[3];
    const float* Bl = (const float*)d_in[4];
    const float* W2 = (const float*)d_in[5];
    const float* b2 = (const float*)d_in[6];
    float* out = (float*)d_out;

    const size_t wb_bytes   = (size_t)M_HID * D_IN * 2;        // 8 MiB
    const size_t part_bytes = (size_t)2 * BATCH * sizeof(float); // 128 KiB

    if (ws_size >= wb_bytes + part_bytes) {
        unsigned short* wb = (unsigned short*)d_ws;
        float* part = (float*)((char*)d_ws + wb_bytes);
        hipLaunchKernelGGL(k_wprep, dim3(M_HID * D_IN / 8 / 256), dim3(256), 0, stream,
                           W0, A, Bl, wb);
        hipLaunchKernelGGL(k_strip128, dim3(256), dim3(512), 0, stream,
                           x, wb, b0, W2, part);
        hipLaunchKernelGGL(k_reduce, dim3(BATCH / 256), dim3(256), 0, stream,
                           part, b2, out);
    } else if (ws_size >= wb_bytes) {
        unsigned short* wb = (unsigned short*)d_ws;
        hipLaunchKernelGGL(k_wprep, dim3(M_HID * D_IN / 8 / 256), dim3(256), 0, stream,
                           W0, A, Bl, wb);
        hipLaunchKernelGGL(k_strip, dim3(BATCH / STRIP), dim3(NTHREADS), 0, stream,
                           x, wb, b0, W2, b2, out);
    } else {
        hipLaunchKernelGGL(k_naive, dim3(BATCH), dim3(256), 0, stream,
                           x, W0, b0, A, Bl, W2, b2, out);
    }
}

// Round 2
// 267.110 us; speedup vs baseline: 1.1571x; 1.1571x over previous
//
#include <hip/hip_runtime.h>
#include <hip/hip_bf16.h>
#include <stdint.h>

// Problem constants (fixed by the reference setup_inputs)
#define BATCH  16384
#define D_IN   1024
#define M_HID  4096
#define R_LORA 16
#define SCALING 2.0f   // ALPHA/R = 32/16

// R7: back to the proven R5 structure (64-row resident strip, zero-barrier
// K-loop, depth-4 wf register ring) with ONE structural change: 16 waves per
// block (1024 thr) = 4 waves/SIMD. R5's counters showed MfmaUtil 42% with a
// ~430-cyc unhidden-latency stall per 256 MFMA-cycles at only 2 waves/SIMD
// (Occupancy 22.5%); doubling TLP is the direct fix. VGPR budget for the
// 128-reg cap: acc[2][2]=64 + wf ring 32 + af 8 + addr/scalars ~20 -> ~124.
// rowpart regs dropped (would overflow): per-pass fold into wave-private LDS.
// Staging uses the R6 XOR pattern that measured 0 bank conflicts; hot loop is
// branch-free (main 0..59 unconditional prefetch + 4-iter tail).

typedef __bf16 bf16x8 __attribute__((ext_vector_type(8)));
typedef float  f32x16 __attribute__((ext_vector_type(16)));

__device__ __forceinline__ unsigned f2bf(float f) {
    union { float f; unsigned u; } c; c.f = f;
    unsigned u = c.u;
    return ((u + 0x7FFFu + ((u >> 16) & 1u)) >> 16);
}

// ---------------- prep: W_eff -> fragment-ordered bf16 ----------------
// Layout (shorts): n32*32768 + c*256 + rl*8 holds W_eff[n32*32+rl][c*8 .. c*8+8).
// R5 mapping (coalesced writes, 2x-amplified W0 reads ~ +17MB HBM, acceptable).
// B-row loads vectorized to 4 x float4 (was 16 scalar uncoalesced loads).
__global__ __launch_bounds__(256) void k_wprep(
    const float* __restrict__ W0, const float* __restrict__ A,
    const float* __restrict__ Bl, unsigned short* __restrict__ wb)
{
    int id = blockIdx.x * 256 + threadIdx.x;        // 524288 total
    int rl  = id & 31;
    int c   = (id >> 5) & 127;
    int n32 = id >> 12;
    int n = n32 * 32 + rl, k0 = c * 8;
    const float* wr = W0 + (size_t)n * D_IN + k0;
    float4 v0 = *(const float4*)(wr);
    float4 v1 = *(const float4*)(wr + 4);
    const float* brow = Bl + n * R_LORA;
    float4 bb[4];
    bb[0] = *(const float4*)(brow);
    bb[1] = *(const float4*)(brow + 4);
    bb[2] = *(const float4*)(brow + 8);
    bb[3] = *(const float4*)(brow + 12);
    const float bs[16] = { bb[0].x, bb[0].y, bb[0].z, bb[0].w,
                           bb[1].x, bb[1].y, bb[1].z, bb[1].w,
                           bb[2].x, bb[2].y, bb[2].z, bb[2].w,
                           bb[3].x, bb[3].y, bb[3].z, bb[3].w };
#pragma unroll
    for (int r = 0; r < R_LORA; ++r) {
        float s = SCALING * bs[r];
        const float* ar = A + r * D_IN + k0;
        float4 a0 = *(const float4*)(ar);
        float4 a1 = *(const float4*)(ar + 4);
        v0.x += s * a0.x; v0.y += s * a0.y; v0.z += s * a0.z; v0.w += s * a0.w;
        v1.x += s * a1.x; v1.y += s * a1.y; v1.z += s * a1.z; v1.w += s * a1.w;
    }
    uint4 o;
    o.x = f2bf(v0.x) | (f2bf(v0.y) << 16);
    o.y = f2bf(v0.z) | (f2bf(v0.w) << 16);
    o.z = f2bf(v1.x) | (f2bf(v1.y) << 16);
    o.w = f2bf(v1.z) | (f2bf(v1.w) << 16);
    ((uint4*)wb)[id] = o;
}

// ---------------- main fused kernel: 64 rows x 4096 cols, 16 waves ----------------
// As layout (shorts): row*1024 + ((oct ^ (row&31))<<3) holds x[row0+row][oct*8..+8)
// in bf16 -- the R6 pattern that measured SQ_LDS_BANK_CONFLICT = 0.
__global__ __launch_bounds__(1024, 4) void k_strip(
    const float* __restrict__ xf, const unsigned short* __restrict__ wb,
    const float* __restrict__ b0, const float* __restrict__ W2,
    const float* __restrict__ b2, float* __restrict__ out)
{
    __shared__ unsigned short As[64 * 1024];   // 128 KiB
    __shared__ float red[16][64];              // 4 KiB wave-private fold rows

    const int tid  = threadIdx.x;
    const int lane = tid & 63;
    const int wave = tid >> 6;      // 0..15
    const int rl   = lane & 31;
    const int half = lane >> 5;
    const int row0 = blockIdx.x * 64;

    // zero the fold accumulator (covered by the staging barrier)
    ((float*)red)[tid] = 0.f;

    // ---- phase 1: x fp32 -> bf16 into resident LDS strip ----
    // idx = j*1024 + tid: so8 = idx&127 (octet), r = idx>>7 (row 0..63).
    // Global reads: per wave 2 KiB contiguous (coalesced).
    {
        const int so8 = tid & 127;
        const int rb  = tid >> 7;           // 0..7
        const float* xsrc = xf + (size_t)row0 * D_IN + so8 * 8;
#pragma unroll
        for (int j = 0; j < 8; ++j) {
            const int r = j * 8 + rb;
            const float* p = xsrc + (size_t)r * D_IN;
            float4 v0 = *(const float4*)(p);
            float4 v1 = *(const float4*)(p + 4);
            uint4 o;
            o.x = f2bf(v0.x) | (f2bf(v0.y) << 16);
            o.y = f2bf(v0.z) | (f2bf(v0.w) << 16);
            o.z = f2bf(v1.x) | (f2bf(v1.y) << 16);
            o.w = f2bf(v1.z) | (f2bf(v1.w) << 16);
            *(uint4*)(&As[r * 1024 + ((so8 ^ (r & 31)) << 3)]) = o;
        }
    }
    __syncthreads();   // the only barrier before the final reduce

    // ---- main: 4 passes x zero-barrier K-loop ----
    for (int pass = 0; pass < 4; ++pass) {
        const int n0 = pass * 1024 + wave * 64;
        const float w2a = W2[n0 + rl],      b0a = b0[n0 + rl];
        const float w2b = W2[n0 + 32 + rl], b0b = b0[n0 + 32 + rl];
        const int n32 = n0 >> 5;
        const unsigned short* w0p = wb + (size_t)n32 * 32768 + half * 256 + rl * 8;
        const unsigned short* w1p = w0p + 32768;

        f32x16 acc[2][2] = {};
        bf16x8 wf0[4], wf1[4];
#pragma unroll
        for (int p = 0; p < 4; ++p) {              // distance-4 register prefetch
            wf0[p] = *(const bf16x8*)(w0p + p * 512);
            wf1[p] = *(const bf16x8*)(w1p + p * 512);
        }

        // main loop: unconditional prefetch (branch-free bodies)
#pragma unroll 4
        for (int kk = 0; kk < 60; ++kk) {
            const int cur = kk & 3;
            const int oc  = kk * 2 + half;
            bf16x8 af0 = *(const bf16x8*)(&As[rl * 1024 + ((oc ^ rl) << 3)]);
            bf16x8 af1 = *(const bf16x8*)(&As[(32 + rl) * 1024 + ((oc ^ rl) << 3)]);
            bf16x8 w0c = wf0[cur], w1c = wf1[cur];
            wf0[cur] = *(const bf16x8*)(w0p + (kk + 4) * 512);
            wf1[cur] = *(const bf16x8*)(w1p + (kk + 4) * 512);
            acc[0][0] = __builtin_amdgcn_mfma_f32_32x32x16_bf16(af0, w0c, acc[0][0], 0, 0, 0);
            acc[0][1] = __builtin_amdgcn_mfma_f32_32x32x16_bf16(af0, w1c, acc[0][1], 0, 0, 0);
            acc[1][0] = __builtin_amdgcn_mfma_f32_32x32x16_bf16(af1, w0c, acc[1][0], 0, 0, 0);
            acc[1][1] = __builtin_amdgcn_mfma_f32_32x32x16_bf16(af1, w1c, acc[1][1], 0, 0, 0);
        }
        // tail: consume the last 4 ring entries, no prefetch
#pragma unroll
        for (int kk = 60; kk < 64; ++kk) {
            const int cur = kk & 3;
            const int oc  = kk * 2 + half;
            bf16x8 af0 = *(const bf16x8*)(&As[rl * 1024 + ((oc ^ rl) << 3)]);
            bf16x8 af1 = *(const bf16x8*)(&As[(32 + rl) * 1024 + ((oc ^ rl) << 3)]);
            acc[0][0] = __builtin_amdgcn_mfma_f32_32x32x16_bf16(af0, wf0[cur], acc[0][0], 0, 0, 0);
            acc[0][1] = __builtin_amdgcn_mfma_f32_32x32x16_bf16(af0, wf1[cur], acc[0][1], 0, 0, 0);
            acc[1][0] = __builtin_amdgcn_mfma_f32_32x32x16_bf16(af1, wf0[cur], acc[1][0], 0, 0, 0);
            acc[1][1] = __builtin_amdgcn_mfma_f32_32x32x16_bf16(af1, wf1[cur], acc[1][1], 0, 0, 0);
        }

        // fold this pass: relu(h + b0) dot W2, shuffle-reduce the 32 col-lanes,
        // accumulate into this wave's private LDS row (no cross-wave races).
        // C/D layout (m74/m101): col = lane&31, row = (r&3) + 8*(r>>2) + 4*half
#pragma unroll
        for (int ti = 0; ti < 2; ++ti)
#pragma unroll
            for (int r = 0; r < 16; ++r) {
                float p = fmaxf(acc[ti][0][r] + b0a, 0.f) * w2a
                        + fmaxf(acc[ti][1][r] + b0b, 0.f) * w2b;
#pragma unroll
                for (int m = 1; m <= 16; m <<= 1)
                    p += __shfl_xor(p, m, 64);        // stays within each 32-half
                if (rl == 0)
                    red[wave][ti * 32 + (r & 3) + 8 * (r >> 2) + 4 * half] += p;
            }
    }

    __syncthreads();
    if (tid < 64) {
        float s = b2[0];
#pragma unroll
        for (int w = 0; w < 16; ++w) s += red[w][tid];
        out[row0 + tid] = s;
    }
}

// ---------------- naive fallback (correctness only; ws too small) ----------------
__global__ __launch_bounds__(256) void k_naive(
    const float* __restrict__ x, const float* __restrict__ W0,
    const float* __restrict__ b0, const float* __restrict__ A,
    const float* __restrict__ Bl, const float* __restrict__ W2,
    const float* __restrict__ b2, float* __restrict__ out)
{
    __shared__ float xs[D_IN];
    int b = blockIdx.x;
    for (int d = threadIdx.x; d < D_IN; d += 256) xs[d] = x[(size_t)b * D_IN + d];
    __syncthreads();
    float part = 0.f;
    for (int m = threadIdx.x; m < M_HID; m += 256) {
        float h = b0[m];
        const float* wr = W0 + (size_t)m * D_IN;
        const float* brow = Bl + m * R_LORA;
        for (int d = 0; d < D_IN; ++d) {
            float w = wr[d];
            for (int r = 0; r < R_LORA; ++r) w += SCALING * brow[r] * A[r * D_IN + d];
            h += xs[d] * w;
        }
        part += fmaxf(h, 0.f) * W2[m];
    }
    __shared__ float sred[256];
    sred[threadIdx.x] = part;
    __syncthreads();
    for (int s = 128; s > 0; s >>= 1) {
        if (threadIdx.x < s) sred[threadIdx.x] += sred[threadIdx.x + s];
        __syncthreads();
    }
    if (threadIdx.x == 0) out[b] = sred[0] + b2[0];
}

// ---------------- host ----------------
extern "C" void kernel_launch(void* const* d_in, const int* in_sizes, int n_in,
                              void* d_out, int out_size, void* d_ws, size_t ws_size,
                              hipStream_t stream) {
    const float* x  = (const float*)d_in[0];
    const float* W0 = (const float*)d_in[1];
    const float* b0 = (const float*)d_in[2];
    const float* A  = (const float*)d_in[3];
    const float* Bl = (const float*)d_in[4];
    const float* W2 = (const float*)d_in[5];
    const float* b2 = (const float*)d_in[6];
    float* out = (float*)d_out;

    const size_t wb_bytes = (size_t)M_HID * D_IN * 2;   // 8 MiB fragment-ordered W_eff
    if (ws_size >= wb_bytes) {
        unsigned short* wb = (unsigned short*)d_ws;
        hipLaunchKernelGGL(k_wprep, dim3(M_HID * D_IN / 8 / 256), dim3(256), 0, stream,
                           W0, A, Bl, wb);
        hipLaunchKernelGGL(k_strip, dim3(BATCH / 64), dim3(1024), 0, stream,
                           x, wb, b0, W2, b2, out);
    } else {
        hipLaunchKernelGGL(k_naive, dim3(BATCH), dim3(256), 0, stream,
                           x, W0, b0, A, Bl, W2, b2, out);
    }
}